// Round 4
// baseline (4355.358 us; speedup 1.0000x reference)
//
#include <hip/hip_runtime.h>

// LSTM T=512, B=32, H=512, L=2. fp16 compute, fp32 accumulate/state.
// Phase A: xproj[t,b,:] = x @ Wih0^T + bih0 + bhh0  (fp16 MFMA GEMM, bias folded)
// Phase B: fused persistent kernel, 128 WGs x 128 thr (2 waves):
//   blocks 0..63   layer 0: z = xproj (precomputed) + h0@Whh0^T
//   blocks 64..127 layer 1: z = h0seq[t]@Wih1^T + h1@Whh1^T + b1 (pipelined)
// Sync: one epoch counter/layer; per-WAVE publish = s_waitcnt vmcnt(0) +
// lane0 relaxed fetch_add (target 128*t). Write-through h stores, per-t
// unique slots, Zs double-buffered => ONE __syncthreads per step, no fences.

typedef _Float16 half8_t __attribute__((ext_vector_type(8)));
typedef _Float16 half4_t __attribute__((ext_vector_type(4)));
typedef _Float16 half2_t __attribute__((ext_vector_type(2)));
typedef float f32x4 __attribute__((ext_vector_type(4)));
typedef unsigned int u32;
typedef unsigned short u16;

#define T_LEN 512
#define BATCH 32
#define HID 512
#define SLOT 16384           // BATCH*HID elems per timestep slot
#define LW (2048 * 512)      // per-layer weight elems

__device__ __forceinline__ float fast_sigmoid(float x) {
  return 1.f / (1.f + __expf(-x));
}
__device__ __forceinline__ float fast_tanh(float x) {
  return 1.f - 2.f / (1.f + __expf(2.f * x));
}
__device__ __forceinline__ u32 epoch_peek(const u32* p) {
  return __hip_atomic_load(p, __ATOMIC_RELAXED, __HIP_MEMORY_SCOPE_AGENT);
}
__device__ __forceinline__ void async_copy16(const void* gsrc, void* ldst) {
  __builtin_amdgcn_global_load_lds(
      (const __attribute__((address_space(1))) u32*)gsrc,
      (__attribute__((address_space(3))) u32*)ldst,
      16, 0, 0);
}

// ---------------- convert fp32 -> fp16 weights ----------------
__global__ __launch_bounds__(256) void convert_w(
    const float4* __restrict__ wih, const float4* __restrict__ whh,
    half4_t* __restrict__ wihh, half4_t* __restrict__ whhh) {
  const int N4W = 524288;  // 2*2048*512 / 4
  int gid = blockIdx.x * 256 + threadIdx.x;
  for (int i = gid; i < 2 * N4W; i += gridDim.x * 256) {
    float4 v;
    half4_t* dst;
    if (i < N4W) { v = wih[i]; dst = wihh + i; }
    else { v = whh[i - N4W]; dst = whhh + (i - N4W); }
    half4_t h;
    h[0] = (_Float16)v.x; h[1] = (_Float16)v.y; h[2] = (_Float16)v.z; h[3] = (_Float16)v.w;
    *dst = h;
  }
}

// ---------------- GEMM: xproj[16384][2048] = x[16384][512]fp32 @ Wih0^T + b ----
// 128x128 tile, BK=64. A staged via fp32 load + convert + ds_write; B via
// global_load_lds width 16. LDS 16B-chunk XOR swizzle: phys chunk = c ^ (m&7).
__global__ __launch_bounds__(256) void gemm_xproj(
    const float* __restrict__ A, const _Float16* __restrict__ W,
    const float* __restrict__ bih, const float* __restrict__ bhh,
    _Float16* __restrict__ C) {
  __shared__ _Float16 As[128 * 64];
  __shared__ _Float16 Bs[128 * 64];
  int bx = blockIdx.x;
  int tn = bx & 15, tm = bx >> 4;
  int m0 = tm * 128, n0 = tn * 128;
  int tid = threadIdx.x, wv = tid >> 6, ln = tid & 63;
  int wm = wv & 1, wn = wv >> 1;
  int q = ln >> 4, cc = ln & 15;
  int am = tid >> 1, afq0 = (tid & 1) * 8;
  f32x4 acc[4][4] = {};
  for (int k0 = 0; k0 < 512; k0 += 64) {
    // A: fp32 -> fp16 staged (8 float4 per thread)
#pragma unroll
    for (int i = 0; i < 8; ++i) {
      int fq = afq0 + i;
      float4 v = *(const float4*)(A + (size_t)(m0 + am) * 512 + k0 + fq * 4);
      half4_t h;
      h[0] = (_Float16)v.x; h[1] = (_Float16)v.y; h[2] = (_Float16)v.z; h[3] = (_Float16)v.w;
      int c = fq >> 1, sub = fq & 1;
      *(half4_t*)(As + am * 64 + (c ^ (am & 7)) * 8 + sub * 4) = h;
    }
    // B: async 16B direct-to-LDS
#pragma unroll
    for (int j = 0; j < 4; ++j) {
      int p = (wv * 4 + j) * 64 + ln;
      int m = p >> 3, pc = p & 7, kg = pc ^ (m & 7);
      async_copy16(W + (size_t)(n0 + m) * 512 + k0 + kg * 8, (void*)(Bs + (p - ln) * 8));
    }
    __syncthreads();
    for (int kc = 0; kc < 2; ++kc) {
      half8_t af[4], bf[4];
#pragma unroll
      for (int i = 0; i < 4; ++i) {
        int m = wm * 64 + i * 16 + cc;
        int kg = (kc * 4 + q) ^ (m & 7);
        af[i] = *(const half8_t*)(As + m * 64 + kg * 8);
        int n = wn * 64 + i * 16 + cc;
        int kg2 = (kc * 4 + q) ^ (n & 7);
        bf[i] = *(const half8_t*)(Bs + n * 64 + kg2 * 8);
      }
#pragma unroll
      for (int i = 0; i < 4; ++i)
#pragma unroll
        for (int j2 = 0; j2 < 4; ++j2)
          acc[i][j2] = __builtin_amdgcn_mfma_f32_16x16x32_f16(af[i], bf[j2], acc[i][j2], 0, 0, 0);
    }
    __syncthreads();
  }
#pragma unroll
  for (int j2 = 0; j2 < 4; ++j2) {
    int n = n0 + wn * 64 + j2 * 16 + cc;
    float bv = bih[n] + bhh[n];
#pragma unroll
    for (int i = 0; i < 4; ++i) {
      int mbase = m0 + wm * 64 + i * 16 + q * 4;
#pragma unroll
      for (int r = 0; r < 4; ++r)
        C[(size_t)(mbase + r) * 2048 + n] = (_Float16)(acc[i][j2][r] + bv);
    }
  }
}

// ---------------- fused 2-layer pipelined recurrence ----------------
__global__ __launch_bounds__(128, 1) void lstm_fused(
    const _Float16* __restrict__ xproj,  // [16384][2048] fp16, bias folded
    const _Float16* __restrict__ wih16,  // [2][2048][512] (layer1 uses +LW)
    const _Float16* __restrict__ whh16,  // [2][2048][512]
    const float* __restrict__ bih, const float* __restrict__ bhh,
    _Float16* h0seq,                     // [T+1][SLOT], slot0 zeroed
    _Float16* h1seq,                     // [T+1][SLOT], slot0 zeroed
    u32* epoch0, u32* epoch1,            // zeroed, own cache lines
    float* outf) {                       // [T][B][H] fp32
  int bid = blockIdx.x;
  int layer = bid >> 6, wg = bid & 63;
  int tid = threadIdx.x, ln = tid & 63;
  int q = ln >> 4, l15 = ln & 15;
  int m0 = (tid >> 6) * 16;            // wave's batch base
  int cb = tid >> 2, cp = tid & 3;     // elem mapping
  int col0 = wg * 8 + cp * 2;

  // persistent W_hh fragments (both layers)
  const _Float16* whh_l = whh16 + (size_t)layer * LW;
  half8_t wh[2][16];
#pragma unroll
  for (int j = 0; j < 2; ++j) {
    int nl = j * 16 + l15;
    int grow = (nl >> 3) * 512 + wg * 8 + (nl & 7);
    size_t ro = (size_t)grow * 512;
#pragma unroll
    for (int kc = 0; kc < 16; ++kc)
      wh[j][kc] = *(const half8_t*)(whh_l + ro + kc * 32 + q * 8);
  }
  // layer-1 only: W_ih fragments + bias
  half8_t wx[2][16];
  float bv[2] = {0.f, 0.f};
  if (layer) {
    const _Float16* wih_l = wih16 + (size_t)LW;
#pragma unroll
    for (int j = 0; j < 2; ++j) {
      int nl = j * 16 + l15;
      int grow = (nl >> 3) * 512 + wg * 8 + (nl & 7);
      size_t ro = (size_t)grow * 512;
#pragma unroll
      for (int kc = 0; kc < 16; ++kc)
        wx[j][kc] = *(const half8_t*)(wih_l + ro + kc * 32 + q * 8);
      bv[j] = bih[2048 + grow] + bhh[2048 + grow];
    }
  }

  _Float16* hself = layer ? h1seq : h0seq;
  u32* eself = layer ? epoch1 : epoch0;
  float cst0 = 0.f, cst1 = 0.f;

  __shared__ float Zs[2][1188];  // double-buffered: [gate]*297 + b*9 + c

  for (int t = 1; t <= T_LEN; ++t) {
    int par = t & 1;
    f32x4 acc0 = {}, acc1 = {};
    half8_t af[16];
    u32 zxw[4];

    if (layer == 0) {
      // prefetch this thread's 8 z_x values (fp16 pairs), then wait
      const _Float16* zxp = xproj + (size_t)((t - 1) * 32 + cb) * 2048 + col0;
#pragma unroll
      for (int g = 0; g < 4; ++g) zxw[g] = *(const u32*)(zxp + g * 512);
      u32 tgt = 128u * (u32)(t - 1);
      while (epoch_peek(epoch0) < tgt) { __builtin_amdgcn_s_sleep(1); }
      asm volatile("" ::: "memory");
    } else {
      u32 tgt0 = 128u * (u32)t, tgt1 = 128u * (u32)(t - 1);
      while (epoch_peek(epoch0) < tgt0 || epoch_peek(epoch1) < tgt1) {
        __builtin_amdgcn_s_sleep(1);
      }
      asm volatile("" ::: "memory");
      const _Float16* xsrc = h0seq + (size_t)t * SLOT;
#pragma unroll
      for (int kc = 0; kc < 16; ++kc)
        af[kc] = *(const half8_t*)(xsrc + (m0 + l15) * HID + kc * 32 + q * 8);
#pragma unroll
      for (int kc = 0; kc < 16; ++kc) {
        acc0 = __builtin_amdgcn_mfma_f32_16x16x32_f16(af[kc], wx[0][kc], acc0, 0, 0, 0);
        acc1 = __builtin_amdgcn_mfma_f32_16x16x32_f16(af[kc], wx[1][kc], acc1, 0, 0, 0);
      }
    }

    // h-part
    const _Float16* hsrc = hself + (size_t)(t - 1) * SLOT;
#pragma unroll
    for (int kc = 0; kc < 16; ++kc)
      af[kc] = *(const half8_t*)(hsrc + (m0 + l15) * HID + kc * 32 + q * 8);
#pragma unroll
    for (int kc = 0; kc < 16; ++kc) {
      acc0 = __builtin_amdgcn_mfma_f32_16x16x32_f16(af[kc], wh[0][kc], acc0, 0, 0, 0);
      acc1 = __builtin_amdgcn_mfma_f32_16x16x32_f16(af[kc], wh[1][kc], acc1, 0, 0, 0);
    }

    // gate exchange (double-buffered LDS)
#pragma unroll
    for (int j = 0; j < 2; ++j) {
      int nl = j * 16 + l15, g = nl >> 3, c = nl & 7;
      const f32x4& a = j ? acc1 : acc0;
#pragma unroll
      for (int r = 0; r < 4; ++r)
        Zs[par][g * 297 + (m0 + q * 4 + r) * 9 + c] = a[r] + bv[j];
    }
    __syncthreads();

    // elementwise: thread owns (cb, col0, col0+1)
    float h0, h1;
    {
      float zi0 = Zs[par][0 * 297 + cb * 9 + cp * 2], zi1 = Zs[par][0 * 297 + cb * 9 + cp * 2 + 1];
      float zf0 = Zs[par][1 * 297 + cb * 9 + cp * 2], zf1 = Zs[par][1 * 297 + cb * 9 + cp * 2 + 1];
      float zg0 = Zs[par][2 * 297 + cb * 9 + cp * 2], zg1 = Zs[par][2 * 297 + cb * 9 + cp * 2 + 1];
      float zo0 = Zs[par][3 * 297 + cb * 9 + cp * 2], zo1 = Zs[par][3 * 297 + cb * 9 + cp * 2 + 1];
      if (layer == 0) {
        half2_t z0 = __builtin_bit_cast(half2_t, zxw[0]);
        half2_t z1 = __builtin_bit_cast(half2_t, zxw[1]);
        half2_t z2 = __builtin_bit_cast(half2_t, zxw[2]);
        half2_t z3 = __builtin_bit_cast(half2_t, zxw[3]);
        zi0 += (float)z0[0]; zi1 += (float)z0[1];
        zf0 += (float)z1[0]; zf1 += (float)z1[1];
        zg0 += (float)z2[0]; zg1 += (float)z2[1];
        zo0 += (float)z3[0]; zo1 += (float)z3[1];
      }
      float i0 = fast_sigmoid(zi0), f0 = fast_sigmoid(zf0), g0 = fast_tanh(zg0), o0 = fast_sigmoid(zo0);
      float i1 = fast_sigmoid(zi1), f1 = fast_sigmoid(zf1), g1 = fast_tanh(zg1), o1 = fast_sigmoid(zo1);
      cst0 = f0 * cst0 + i0 * g0;
      cst1 = f1 * cst1 + i1 * g1;
      h0 = o0 * fast_tanh(cst0);
      h1 = o1 * fast_tanh(cst1);
      u32 hp = (u32)__builtin_bit_cast(u16, (_Float16)h0) |
               ((u32)__builtin_bit_cast(u16, (_Float16)h1) << 16);
      u32* hdst = (u32*)(hself + (size_t)t * SLOT + cb * HID + col0);
      __hip_atomic_store(hdst, hp, __ATOMIC_RELAXED, __HIP_MEMORY_SCOPE_AGENT);
    }
    // per-wave publish: drain own write-through stores, then one add
    asm volatile("s_waitcnt vmcnt(0)" ::: "memory");
    if (ln == 0)
      (void)__hip_atomic_fetch_add(eself, 1u, __ATOMIC_RELAXED, __HIP_MEMORY_SCOPE_AGENT);
    // fp32 out store after publish (nobody consumes it on-device)
    if (layer) {
      float2 o2; o2.x = h0; o2.y = h1;
      *(float2*)(outf + (size_t)(t - 1) * SLOT + cb * HID + col0) = o2;
    }
  }
}

extern "C" void kernel_launch(void* const* d_in, const int* in_sizes, int n_in,
                              void* d_out, int out_size, void* d_ws, size_t ws_size,
                              hipStream_t stream) {
  const float* x = (const float*)d_in[0];
  const float* Wih = (const float*)d_in[1];
  const float* Whh = (const float*)d_in[2];
  const float* bih = (const float*)d_in[3];
  const float* bhh = (const float*)d_in[4];
  char* ws = (char*)d_ws;
  // ws layout (bytes)
  const size_t OFF_XPROJ = 0;                 // 16384*2048*2 = 67,108,864
  const size_t OFF_H0 = 67108864;             // 513*32768 = 16,809,984
  const size_t OFF_H1 = 83918848;             // 16,809,984
  const size_t OFF_WIH = 100728832;           // 4,194,304
  const size_t OFF_WHH = 104923136;           // 4,194,304
  const size_t OFF_EPOCH = 109117440;         // 512
  const size_t TOTAL = 109117952;
  if (ws_size < TOTAL) return;
  _Float16* xproj = (_Float16*)(ws + OFF_XPROJ);
  _Float16* h0seq = (_Float16*)(ws + OFF_H0);
  _Float16* h1seq = (_Float16*)(ws + OFF_H1);
  _Float16* wihh = (_Float16*)(ws + OFF_WIH);
  _Float16* whhh = (_Float16*)(ws + OFF_WHH);
  u32* epoch0 = (u32*)(ws + OFF_EPOCH);
  u32* epoch1 = (u32*)(ws + OFF_EPOCH + 256);

  hipMemsetAsync(ws + OFF_EPOCH, 0, 512, stream);
  hipMemsetAsync(ws + OFF_H0, 0, 32768, stream);
  hipMemsetAsync(ws + OFF_H1, 0, 32768, stream);
  convert_w<<<2048, 256, 0, stream>>>((const float4*)Wih, (const float4*)Whh,
                                      (half4_t*)wihh, (half4_t*)whhh);
  gemm_xproj<<<2048, 256, 0, stream>>>(x, wihh, bih, bhh, xproj);
  lstm_fused<<<128, 128, 0, stream>>>(xproj, wihh, whhh, bih, bhh,
                                      h0seq, h1seq, epoch0, epoch1, (float*)d_out);
}

// Round 7
// 3764.698 us; speedup vs baseline: 1.1569x; 1.1569x over previous
//
#include <hip/hip_runtime.h>

// LSTM T=512, B=32, H=512, L=2. fp16 compute, fp32 accumulate/state.
// Round-3 structure + poll-pressure cut (hang-safe variant):
//   (a) only wave 0 of each WG polls the global epoch counters; wave 1 waits
//       at a __syncthreads() barrier (parked waves issue no traffic);
//   (b) s_sleep(8) backoff between polls.
// Pollers: 256 waves -> 128, each at ~half rate (~3.5x less TCC pressure).
//
// 128 WGs x 128 thr: blocks 0..63 layer 0, 64..127 layer 1 (pipelined).
// One epoch counter per layer; producers publish via tid0 relaxed fetch_add
// after a vmcnt-drained barrier; "all WGs done step s" <=> epoch >= 64*s.
// Write-through h stores + per-t unique slots => no fences anywhere.

typedef _Float16 half8_t __attribute__((ext_vector_type(8)));
typedef _Float16 half4_t __attribute__((ext_vector_type(4)));
typedef float f32x4 __attribute__((ext_vector_type(4)));
typedef unsigned int u32;
typedef unsigned short u16;

#define T_LEN 512
#define BATCH 32
#define HID 512
#define SLOT 16384           // BATCH*HID elems per timestep slot
#define LW (2048 * 512)      // per-layer weight elems

__device__ __forceinline__ float fast_sigmoid(float x) {
  return 1.f / (1.f + __expf(-x));
}
__device__ __forceinline__ float fast_tanh(float x) {
  return 1.f - 2.f / (1.f + __expf(2.f * x));
}
__device__ __forceinline__ u32 epoch_peek(const u32* p) {
  return __hip_atomic_load(p, __ATOMIC_RELAXED, __HIP_MEMORY_SCOPE_AGENT);
}

// ---------------- convert fp32 -> fp16 (x, Wih, Whh) + bias sum ----------------
__global__ __launch_bounds__(256) void convert_k(
    const float4* __restrict__ x,    // 8388608 floats = 2097152 float4
    const float4* __restrict__ wih,  // 2097152 floats = 524288 float4
    const float4* __restrict__ whh,  // same
    const float* __restrict__ bih, const float* __restrict__ bhh,
    half4_t* __restrict__ xh, half4_t* __restrict__ wihh, half4_t* __restrict__ whhh,
    float* __restrict__ bsum) {
  const int N4X = 2097152, N4W = 524288, TOT = N4X + 2 * N4W;
  int gid = blockIdx.x * 256 + threadIdx.x;
  for (int i = gid; i < TOT; i += gridDim.x * 256) {
    float4 v;
    half4_t* dst;
    if (i < N4X) { v = x[i]; dst = xh + i; }
    else if (i < N4X + N4W) { v = wih[i - N4X]; dst = wihh + (i - N4X); }
    else { v = whh[i - N4X - N4W]; dst = whhh + (i - N4X - N4W); }
    half4_t h;
    h[0] = (_Float16)v.x; h[1] = (_Float16)v.y; h[2] = (_Float16)v.z; h[3] = (_Float16)v.w;
    *dst = h;
  }
  if (gid < 4096) bsum[gid] = bih[gid] + bhh[gid];
}

// ---------------- fused 2-layer pipelined recurrence ----------------
__global__ __launch_bounds__(128, 1) void lstm_fused(
    const _Float16* __restrict__ x0h,   // [T][SLOT]
    const _Float16* __restrict__ wih16, // [2][2048][512]
    const _Float16* __restrict__ whh16, // [2][2048][512]
    const float* __restrict__ bsum,     // [2][2048]
    _Float16* h0seq,                    // [T+1][SLOT], slot0 zeroed
    _Float16* h1seq,                    // [T+1][SLOT], slot0 zeroed
    u32* epoch0, u32* epoch1,           // 1 counter each, own cache line, zeroed
    float* outf) {                      // [T][B][H] fp32
  int bid = blockIdx.x;
  int layer = bid >> 6, wg = bid & 63;
  int tid = threadIdx.x;               // 0..127
  int ln = tid & 63;
  int wv = tid >> 6;
  int q = ln >> 4, l15 = ln & 15;
  int m0 = wv * 16;                    // wave's batch base

  // ---- weight fragments: n=32 = 4 gates x 8 cols ----
  const _Float16* wih_l = wih16 + (size_t)layer * LW;
  const _Float16* whh_l = whh16 + (size_t)layer * LW;
  half8_t wx[2][16], wh[2][16];
  float bv[2];
#pragma unroll
  for (int j = 0; j < 2; ++j) {
    int nl = j * 16 + l15;
    int grow = (nl >> 3) * 512 + wg * 8 + (nl & 7);   // gate*512 + col
    size_t ro = (size_t)grow * 512;
#pragma unroll
    for (int kc = 0; kc < 16; ++kc) {
      wx[j][kc] = *(const half8_t*)(wih_l + ro + kc * 32 + q * 8);
      wh[j][kc] = *(const half8_t*)(whh_l + ro + kc * 32 + q * 8);
    }
    bv[j] = bsum[layer * 2048 + grow];
  }

  const _Float16* xbase = layer ? (h0seq + SLOT) : x0h;  // step t reads xbase+(t-1)*SLOT
  _Float16* hself = layer ? h1seq : h0seq;
  u32* eself = layer ? epoch1 : epoch0;

  // consumer mapping: thread -> (batch cb, col pair cp)
  int cb = tid >> 2;
  int cp = tid & 3;
  int col0 = wg * 8 + cp * 2;
  float cst0 = 0.f, cst1 = 0.f;

  __shared__ float Zs[4 * 297];  // [gate]*297 + b*9 + c   (33*9 per gate)

  for (int t = 1; t <= T_LEN; ++t) {
    const _Float16* xsrc = xbase + (size_t)(t - 1) * SLOT;
    const _Float16* hsrc = hself + (size_t)(t - 1) * SLOT;
    f32x4 acc0 = {}, acc1 = {};
    half8_t af[16];

    if (layer == 0) {
      // x-part: independent of sync — do before waiting
#pragma unroll
      for (int kc = 0; kc < 16; ++kc)
        af[kc] = *(const half8_t*)(xsrc + (m0 + l15) * HID + kc * 32 + q * 8);
#pragma unroll
      for (int kc = 0; kc < 16; ++kc) {
        acc0 = __builtin_amdgcn_mfma_f32_16x16x32_f16(af[kc], wx[0][kc], acc0, 0, 0, 0);
        acc1 = __builtin_amdgcn_mfma_f32_16x16x32_f16(af[kc], wx[1][kc], acc1, 0, 0, 0);
      }
      // wave 0 is the sole poller; wave 1 parks at the barrier below
      if (wv == 0) {
        u32 tgt = 64u * (u32)(t - 1);
        u32 e = epoch_peek(epoch0);
        while (e < tgt) { __builtin_amdgcn_s_sleep(8); e = epoch_peek(epoch0); }
      }
      asm volatile("" ::: "memory");
      __syncthreads();  // barrier A: releases wave 1 once wave 0 saw the flag
      // h-part
#pragma unroll
      for (int kc = 0; kc < 16; ++kc)
        af[kc] = *(const half8_t*)(hsrc + (m0 + l15) * HID + kc * 32 + q * 8);
#pragma unroll
      for (int kc = 0; kc < 16; ++kc) {
        acc0 = __builtin_amdgcn_mfma_f32_16x16x32_f16(af[kc], wh[0][kc], acc0, 0, 0, 0);
        acc1 = __builtin_amdgcn_mfma_f32_16x16x32_f16(af[kc], wh[1][kc], acc1, 0, 0, 0);
      }
    } else {
      // need: layer-0 all done step t (x = h0seq[t]) AND own layer done t-1
      if (wv == 0) {
        u32 tgt0 = 64u * (u32)t, tgt1 = 64u * (u32)(t - 1);
        u32 e0 = epoch_peek(epoch0), e1 = epoch_peek(epoch1);
        while (e0 < tgt0 || e1 < tgt1) {
          __builtin_amdgcn_s_sleep(8);
          e0 = epoch_peek(epoch0);
          e1 = epoch_peek(epoch1);
        }
      }
      asm volatile("" ::: "memory");
      __syncthreads();  // barrier A
#pragma unroll
      for (int kc = 0; kc < 16; ++kc)
        af[kc] = *(const half8_t*)(xsrc + (m0 + l15) * HID + kc * 32 + q * 8);
#pragma unroll
      for (int kc = 0; kc < 16; ++kc) {
        acc0 = __builtin_amdgcn_mfma_f32_16x16x32_f16(af[kc], wx[0][kc], acc0, 0, 0, 0);
        acc1 = __builtin_amdgcn_mfma_f32_16x16x32_f16(af[kc], wx[1][kc], acc1, 0, 0, 0);
      }
      // h-part
#pragma unroll
      for (int kc = 0; kc < 16; ++kc)
        af[kc] = *(const half8_t*)(hsrc + (m0 + l15) * HID + kc * 32 + q * 8);
#pragma unroll
      for (int kc = 0; kc < 16; ++kc) {
        acc0 = __builtin_amdgcn_mfma_f32_16x16x32_f16(af[kc], wh[0][kc], acc0, 0, 0, 0);
        acc1 = __builtin_amdgcn_mfma_f32_16x16x32_f16(af[kc], wh[1][kc], acc1, 0, 0, 0);
      }
    }

    // publish z to LDS: lane's tile j col = nl = j*16+l15 -> gate=nl>>3, c=nl&7
#pragma unroll
    for (int j = 0; j < 2; ++j) {
      int nl = j * 16 + l15, g = nl >> 3, c = nl & 7;
      const f32x4& a = j ? acc1 : acc0;
#pragma unroll
      for (int r = 0; r < 4; ++r)
        Zs[g * 297 + (m0 + q * 4 + r) * 9 + c] = a[r] + bv[j];
    }
    __syncthreads();  // barrier B

    // elementwise: thread owns (cb, col0, col0+1)
    float h0, h1;
    {
      float zi0 = Zs[0 * 297 + cb * 9 + cp * 2], zi1 = Zs[0 * 297 + cb * 9 + cp * 2 + 1];
      float zf0 = Zs[1 * 297 + cb * 9 + cp * 2], zf1 = Zs[1 * 297 + cb * 9 + cp * 2 + 1];
      float zg0 = Zs[2 * 297 + cb * 9 + cp * 2], zg1 = Zs[2 * 297 + cb * 9 + cp * 2 + 1];
      float zo0 = Zs[3 * 297 + cb * 9 + cp * 2], zo1 = Zs[3 * 297 + cb * 9 + cp * 2 + 1];
      float i0 = fast_sigmoid(zi0), f0 = fast_sigmoid(zf0), g0 = fast_tanh(zg0), o0 = fast_sigmoid(zo0);
      float i1 = fast_sigmoid(zi1), f1 = fast_sigmoid(zf1), g1 = fast_tanh(zg1), o1 = fast_sigmoid(zo1);
      cst0 = f0 * cst0 + i0 * g0;
      cst1 = f1 * cst1 + i1 * g1;
      h0 = o0 * fast_tanh(cst0);
      h1 = o1 * fast_tanh(cst1);
      // write-through packed h store (drained by barrier C before publish)
      u32 hp = (u32)__builtin_bit_cast(u16, (_Float16)h0) |
               ((u32)__builtin_bit_cast(u16, (_Float16)h1) << 16);
      u32* hdst = (u32*)(hself + (size_t)t * SLOT + cb * HID + col0);
      __hip_atomic_store(hdst, hp, __ATOMIC_RELAXED, __HIP_MEMORY_SCOPE_AGENT);
    }
    // barrier C: drains each wave's vmcnt (incl. h stores) before the publish
    __syncthreads();
    if (tid == 0)
      (void)__hip_atomic_fetch_add(eself, 1u, __ATOMIC_RELAXED, __HIP_MEMORY_SCOPE_AGENT);
    // out store AFTER publish — nobody consumes it; drain overlaps next step
    if (layer) {
      float2 o2; o2.x = h0; o2.y = h1;
      *(float2*)(outf + (size_t)(t - 1) * SLOT + cb * HID + col0) = o2;
    }
  }
}

extern "C" void kernel_launch(void* const* d_in, const int* in_sizes, int n_in,
                              void* d_out, int out_size, void* d_ws, size_t ws_size,
                              hipStream_t stream) {
  const float* x = (const float*)d_in[0];
  const float* Wih = (const float*)d_in[1];
  const float* Whh = (const float*)d_in[2];
  const float* bih = (const float*)d_in[3];
  const float* bhh = (const float*)d_in[4];
  char* ws = (char*)d_ws;
  // ws layout (bytes)
  const size_t OFF_X0H = 0;                  // 16,777,216
  const size_t OFF_H0SEQ = 16777216;         // 513*32768 = 16,809,984
  const size_t OFF_H1SEQ = 33587200;         // 16,809,984
  const size_t OFF_WIH = 50397184;           // 4,194,304
  const size_t OFF_WHH = 54591488;           // 4,194,304
  const size_t OFF_BSUM = 58785792;          // 16,384
  const size_t OFF_EPOCH0 = 58802176;        // own cache line
  const size_t OFF_EPOCH1 = 58802432;        // own cache line (+256B)
  const size_t TOTAL = 58802688;
  if (ws_size < TOTAL) return;
  _Float16* x0h = (_Float16*)(ws + OFF_X0H);
  _Float16* h0seq = (_Float16*)(ws + OFF_H0SEQ);
  _Float16* h1seq = (_Float16*)(ws + OFF_H1SEQ);
  _Float16* wihh = (_Float16*)(ws + OFF_WIH);
  _Float16* whhh = (_Float16*)(ws + OFF_WHH);
  float* bsum = (float*)(ws + OFF_BSUM);
  u32* epoch0 = (u32*)(ws + OFF_EPOCH0);
  u32* epoch1 = (u32*)(ws + OFF_EPOCH1);

  // zero: epochs + slot0 of both h sequences
  hipMemsetAsync(ws + OFF_EPOCH0, 0, 512, stream);
  hipMemsetAsync(ws + OFF_H0SEQ, 0, 32768, stream);
  hipMemsetAsync(ws + OFF_H1SEQ, 0, 32768, stream);
  convert_k<<<3072, 256, 0, stream>>>((const float4*)x, (const float4*)Wih,
                                      (const float4*)Whh, bih, bhh,
                                      (half4_t*)x0h, (half4_t*)wihh, (half4_t*)whhh, bsum);
  lstm_fused<<<128, 128, 0, stream>>>(x0h, wihh, whhh, bsum, h0seq, h1seq,
                                      epoch0, epoch1, (float*)d_out);
}